// Round 1
// baseline (2181.503 us; speedup 1.0000x reference)
//
#include <hip/hip_runtime.h>
#include <hip/hip_bf16.h>
#include <cstdint>
#include <cstddef>

// Problem constants (match reference)
constexpr int Bc = 32;    // batch
constexpr int Sc = 512;   // source length
constexpr int Hc = 256;   // hidden
constexpr int Fc = 256;   // filter
constexpr int Tc = 2048;  // max mel length
constexpr int Kc = 3;     // conv kernel
constexpr float EPSc = 1e-5f;

constexpr int TP = 16;    // positions per block tile in conv kernels

// ---- output layout (flat f32) ----
constexpr size_t O_OUT   = 0;                                   // (B,T,H)
constexpr size_t O_PP    = O_OUT  + (size_t)Bc*Tc*Hc;           // (B,T)
constexpr size_t O_EP    = O_PP   + (size_t)Bc*Tc;              // (B,T)
constexpr size_t O_LOGD  = O_EP   + (size_t)Bc*Tc;              // (B,S)
constexpr size_t O_DUR   = O_LOGD + (size_t)Bc*Sc;              // (B,S)
constexpr size_t O_MLEN  = O_DUR  + (size_t)Bc*Sc;              // (B,)
constexpr size_t O_MMASK = O_MLEN + (size_t)Bc;                 // (B,T)

// ---- workspace layout (bytes) ----
constexpr size_t W_CUM = 0;                 // int[B*S]
constexpr size_t W_MEL = 0x10000;           // int[B]
constexpr size_t W_IDX = 0x10100;           // int[B*T]
constexpr size_t W_BUF = 0x60000;           // float[B*T*F]

// ============================================================
// 1) per-batch inclusive scan of durations + dur/mel_len outputs
// ============================================================
__global__ void scan_kernel(const int* __restrict__ dur, int* __restrict__ cum,
                            int* __restrict__ mel_i, float* __restrict__ dur_out,
                            float* __restrict__ mlen_out) {
  int b = blockIdx.x;
  int lane = threadIdx.x;                 // blockDim.x == 64
  const int per = Sc / 64;                // 8
  int base = b * Sc + lane * per;
  int v[per];
  int s = 0;
  #pragma unroll
  for (int i = 0; i < per; i++) { v[i] = dur[base + i]; s += v[i]; }
  // inclusive scan of per-lane sums
  int pre = s;
  #pragma unroll
  for (int d = 1; d < 64; d <<= 1) {
    int o = __shfl_up(pre, d, 64);
    if (lane >= d) pre += o;
  }
  int run = pre - s;                      // exclusive prefix
  #pragma unroll
  for (int i = 0; i < per; i++) {
    run += v[i];
    cum[base + i] = run;
    dur_out[base + i] = (float)v[i];
  }
  if (lane == 63) { mel_i[b] = run; mlen_out[b] = (float)run; }
}

// ============================================================
// 2) searchsorted(cum, t, 'right') -> idx ; mel_mask output
// ============================================================
__global__ void idx_kernel(const int* __restrict__ cum, const int* __restrict__ mel_i,
                           int* __restrict__ idx, float* __restrict__ mmask) {
  int gid = blockIdx.x * blockDim.x + threadIdx.x;   // B*T threads
  int b = gid / Tc, t = gid % Tc;
  const int* c = cum + b * Sc;
  int lo = 0, hi = Sc;
  while (lo < hi) {
    int mid = (lo + hi) >> 1;
    if (c[mid] <= t) lo = mid + 1; else hi = mid;
  }
  int i = lo > (Sc - 1) ? (Sc - 1) : lo;
  idx[gid] = i;
  mmask[gid] = (t < mel_i[b]) ? 0.0f : 1.0f;
}

// ============================================================
// Conv1d(K=3,SAME) + ReLU + LayerNorm, output to buffer.
// GATHER: input row t' = valid(t') * (x[b, idx[t'], :] + sc[b,idx]*sc_w + sc_b)
// else:   input row t' = hin[b, t', :]
// ============================================================
template <bool GATHER>
__global__ __launch_bounds__(256) void conv_ln_kernel(
    const float* __restrict__ hin, const float* __restrict__ sc,
    const float* __restrict__ sc_w, const float* __restrict__ sc_b,
    const int* __restrict__ idx, const int* __restrict__ mel_i,
    const float* __restrict__ cw, const float* __restrict__ cb,
    const float* __restrict__ lng, const float* __restrict__ lnb,
    float* __restrict__ hout, int N) {
  __shared__ float in_t[TP + 2][Fc];
  __shared__ float out_t[TP][Fc];
  __shared__ float stats[2][TP];
  const int c = threadIdx.x;              // c_out, 0..255
  const int b = blockIdx.y;
  const int t0 = blockIdx.x * TP;

  // stage input rows (zero-pad SAME boundaries)
  #pragma unroll
  for (int r = 0; r < TP + 2; r++) {
    int t = t0 + r - 1;
    float v = 0.0f;
    if (t >= 0 && t < N) {
      if (GATHER) {
        int i = idx[b * Tc + t];
        if (t < mel_i[b])
          v = hin[((size_t)b * Sc + i) * Hc + c] + sc[b * Sc + i] * sc_w[c] + sc_b[c];
      } else {
        v = hin[((size_t)b * N + t) * Fc + c];
      }
    }
    in_t[r][c] = v;
  }
  __syncthreads();

  float acc[TP];
  float bias = cb[c];
  #pragma unroll
  for (int t = 0; t < TP; t++) acc[t] = bias;

  for (int ci = 0; ci < Fc; ci += 2) {
    float w00 = cw[(0 * Fc + ci) * Fc + c];
    float w01 = cw[(0 * Fc + ci + 1) * Fc + c];
    float w10 = cw[(1 * Fc + ci) * Fc + c];
    float w11 = cw[(1 * Fc + ci + 1) * Fc + c];
    float w20 = cw[(2 * Fc + ci) * Fc + c];
    float w21 = cw[(2 * Fc + ci + 1) * Fc + c];
    float2 hv[TP + 2];
    #pragma unroll
    for (int r = 0; r < TP + 2; r++) hv[r] = *(const float2*)&in_t[r][ci];
    #pragma unroll
    for (int t = 0; t < TP; t++) {
      float a = acc[t];
      a = fmaf(hv[t].x, w00, a);     a = fmaf(hv[t].y, w01, a);
      a = fmaf(hv[t + 1].x, w10, a); a = fmaf(hv[t + 1].y, w11, a);
      a = fmaf(hv[t + 2].x, w20, a); a = fmaf(hv[t + 2].y, w21, a);
      acc[t] = a;
    }
  }

  // ReLU, stash for stats
  #pragma unroll
  for (int t = 0; t < TP; t++) { float v = fmaxf(acc[t], 0.0f); acc[t] = v; out_t[t][c] = v; }
  __syncthreads();

  // LN stats: group g (16 threads) handles position g
  {
    int g = c >> 4, l = c & 15;
    float s = 0.0f, s2 = 0.0f;
    #pragma unroll
    for (int j = l; j < Fc; j += 16) { float v = out_t[g][j]; s += v; s2 += v * v; }
    #pragma unroll
    for (int d = 8; d >= 1; d >>= 1) { s += __shfl_xor(s, d, 64); s2 += __shfl_xor(s2, d, 64); }
    if (l == 0) {
      float m = s * (1.0f / Fc);
      float var = s2 * (1.0f / Fc) - m * m;
      stats[0][g] = m;
      stats[1][g] = rsqrtf(var + EPSc);
    }
  }
  __syncthreads();

  float g_ = lng[c], b_ = lnb[c];
  #pragma unroll
  for (int t = 0; t < TP; t++) {
    float v = (acc[t] - stats[0][t]) * stats[1][t] * g_ + b_;
    hout[((size_t)b * N + t0 + t) * Fc + c] = v;
  }
}

// ============================================================
// Conv1d + ReLU + LN + (h @ lw + lb) projection + mask -> pred
// MASK_MEL: mask = t >= mel_len ; else mask = src_mask[b,t] != 0
// ============================================================
template <bool MASK_MEL>
__global__ __launch_bounds__(256) void conv_ln_proj_kernel(
    const float* __restrict__ hin, const int* __restrict__ mel_i,
    const unsigned char* __restrict__ src_mask,
    const float* __restrict__ cw, const float* __restrict__ cb,
    const float* __restrict__ lng, const float* __restrict__ lnb,
    const float* __restrict__ lw, const float* __restrict__ lb,
    float* __restrict__ pred, int N) {
  __shared__ float in_t[TP + 2][Fc];
  __shared__ float out_t[TP][Fc];
  __shared__ float stats[2][TP];
  const int c = threadIdx.x;
  const int b = blockIdx.y;
  const int t0 = blockIdx.x * TP;

  #pragma unroll
  for (int r = 0; r < TP + 2; r++) {
    int t = t0 + r - 1;
    float v = 0.0f;
    if (t >= 0 && t < N) v = hin[((size_t)b * N + t) * Fc + c];
    in_t[r][c] = v;
  }
  __syncthreads();

  float acc[TP];
  float bias = cb[c];
  #pragma unroll
  for (int t = 0; t < TP; t++) acc[t] = bias;

  for (int ci = 0; ci < Fc; ci += 2) {
    float w00 = cw[(0 * Fc + ci) * Fc + c];
    float w01 = cw[(0 * Fc + ci + 1) * Fc + c];
    float w10 = cw[(1 * Fc + ci) * Fc + c];
    float w11 = cw[(1 * Fc + ci + 1) * Fc + c];
    float w20 = cw[(2 * Fc + ci) * Fc + c];
    float w21 = cw[(2 * Fc + ci + 1) * Fc + c];
    float2 hv[TP + 2];
    #pragma unroll
    for (int r = 0; r < TP + 2; r++) hv[r] = *(const float2*)&in_t[r][ci];
    #pragma unroll
    for (int t = 0; t < TP; t++) {
      float a = acc[t];
      a = fmaf(hv[t].x, w00, a);     a = fmaf(hv[t].y, w01, a);
      a = fmaf(hv[t + 1].x, w10, a); a = fmaf(hv[t + 1].y, w11, a);
      a = fmaf(hv[t + 2].x, w20, a); a = fmaf(hv[t + 2].y, w21, a);
      acc[t] = a;
    }
  }

  #pragma unroll
  for (int t = 0; t < TP; t++) { float v = fmaxf(acc[t], 0.0f); acc[t] = v; out_t[t][c] = v; }
  __syncthreads();

  {
    int g = c >> 4, l = c & 15;
    float s = 0.0f, s2 = 0.0f;
    #pragma unroll
    for (int j = l; j < Fc; j += 16) { float v = out_t[g][j]; s += v; s2 += v * v; }
    #pragma unroll
    for (int d = 8; d >= 1; d >>= 1) { s += __shfl_xor(s, d, 64); s2 += __shfl_xor(s2, d, 64); }
    if (l == 0) {
      float m = s * (1.0f / Fc);
      float var = s2 * (1.0f / Fc) - m * m;
      stats[0][g] = m;
      stats[1][g] = rsqrtf(var + EPSc);
    }
  }
  __syncthreads();

  // LN output * lw -> out_t, then per-position reduction
  float g_ = lng[c], b_ = lnb[c], w_ = lw[c];
  #pragma unroll
  for (int t = 0; t < TP; t++) {
    float v = (acc[t] - stats[0][t]) * stats[1][t] * g_ + b_;
    out_t[t][c] = v * w_;
  }
  __syncthreads();
  {
    int g = c >> 4, l = c & 15;
    float s = 0.0f;
    #pragma unroll
    for (int j = l; j < Fc; j += 16) s += out_t[g][j];
    #pragma unroll
    for (int d = 8; d >= 1; d >>= 1) s += __shfl_xor(s, d, 64);
    if (l == 0) {
      int t = t0 + g;
      float o = s + lb[0];
      bool masked;
      if (MASK_MEL) masked = !(t < mel_i[b]);
      else          masked = (src_mask[b * N + t] != 0);
      pred[(size_t)b * N + t] = masked ? 0.0f : o;
    }
  }
}

// ============================================================
// out = xe + pp*pc2_w + pc2_b + ep*ec2_w + ec2_b
// ============================================================
__global__ __launch_bounds__(256) void final_kernel(
    const float* __restrict__ x, const int* __restrict__ idx,
    const int* __restrict__ mel_i,
    const float* __restrict__ pp, const float* __restrict__ ep,
    const float* __restrict__ pc2_w, const float* __restrict__ pc2_b,
    const float* __restrict__ ec2_w, const float* __restrict__ ec2_b,
    float* __restrict__ out) {
  int bt = blockIdx.x;                  // B*T blocks
  int b = bt / Tc, t = bt % Tc;
  int c = threadIdx.x;
  int i = idx[bt];
  float xe = (t < mel_i[b]) ? x[((size_t)b * Sc + i) * Hc + c] : 0.0f;
  float o = xe + pp[bt] * pc2_w[c] + pc2_b[c] + ep[bt] * ec2_w[c] + ec2_b[c];
  out[(size_t)bt * Hc + c] = o;
}

// ============================================================
extern "C" void kernel_launch(void* const* d_in, const int* in_sizes, int n_in,
                              void* d_out, int out_size, void* d_ws, size_t ws_size,
                              hipStream_t stream) {
  const float* x          = (const float*)d_in[0];
  const unsigned char* sm = (const unsigned char*)d_in[1];
  const float* src_pitch  = (const float*)d_in[3];
  const float* src_energy = (const float*)d_in[4];
  const int*   src_dur    = (const int*)d_in[5];

  const float* dur_cw = (const float*)d_in[7];
  const float* dur_cb = (const float*)d_in[8];
  const float* dur_lng= (const float*)d_in[9];
  const float* dur_lnb= (const float*)d_in[10];
  const float* dur_lw = (const float*)d_in[11];
  const float* dur_lb = (const float*)d_in[12];

  const float* pit_cw = (const float*)d_in[13];
  const float* pit_cb = (const float*)d_in[14];
  const float* pit_lng= (const float*)d_in[15];
  const float* pit_lnb= (const float*)d_in[16];
  const float* pit_lw = (const float*)d_in[17];
  const float* pit_lb = (const float*)d_in[18];

  const float* ene_cw = (const float*)d_in[19];
  const float* ene_cb = (const float*)d_in[20];
  const float* ene_lng= (const float*)d_in[21];
  const float* ene_lnb= (const float*)d_in[22];
  const float* ene_lw = (const float*)d_in[23];
  const float* ene_lb = (const float*)d_in[24];

  const float* pc1_w = (const float*)d_in[25];
  const float* pc1_b = (const float*)d_in[26];
  const float* pc2_w = (const float*)d_in[27];
  const float* pc2_b = (const float*)d_in[28];
  const float* ec1_w = (const float*)d_in[29];
  const float* ec1_b = (const float*)d_in[30];
  const float* ec2_w = (const float*)d_in[31];
  const float* ec2_b = (const float*)d_in[32];

  float* out = (float*)d_out;
  float* o_out   = out + O_OUT;
  float* o_pp    = out + O_PP;
  float* o_ep    = out + O_EP;
  float* o_logd  = out + O_LOGD;
  float* o_dur   = out + O_DUR;
  float* o_mlen  = out + O_MLEN;
  float* o_mmask = out + O_MMASK;

  char* ws = (char*)d_ws;
  int*   w_cum = (int*)(ws + W_CUM);
  int*   w_mel = (int*)(ws + W_MEL);
  int*   w_idx = (int*)(ws + W_IDX);
  float* w_buf = (float*)(ws + W_BUF);

  constexpr int LAYER_W = Kc * Fc * Fc;   // conv weight stride per layer

  // 1) scan + dur/mel_len outputs
  scan_kernel<<<Bc, 64, 0, stream>>>(src_dur, w_cum, w_mel, o_dur, o_mlen);

  // 2) searchsorted + mel_mask output
  idx_kernel<<<(Bc * Tc) / 256, 256, 0, stream>>>(w_cum, w_mel, w_idx, o_mmask);

  dim3 gridT(Tc / TP, Bc);
  dim3 gridS(Sc / TP, Bc);

  // 3) pitch predictor: layer0 (gathered pe) -> buf ; layer1+proj -> pp
  conv_ln_kernel<true><<<gridT, 256, 0, stream>>>(
      x, src_pitch, pc1_w, pc1_b, w_idx, w_mel,
      pit_cw, pit_cb, pit_lng, pit_lnb, w_buf, Tc);
  conv_ln_proj_kernel<true><<<gridT, 256, 0, stream>>>(
      w_buf, w_mel, nullptr,
      pit_cw + LAYER_W, pit_cb + Fc, pit_lng + Fc, pit_lnb + Fc,
      pit_lw, pit_lb, o_pp, Tc);

  // 4) energy predictor
  conv_ln_kernel<true><<<gridT, 256, 0, stream>>>(
      x, src_energy, ec1_w, ec1_b, w_idx, w_mel,
      ene_cw, ene_cb, ene_lng, ene_lnb, w_buf, Tc);
  conv_ln_proj_kernel<true><<<gridT, 256, 0, stream>>>(
      w_buf, w_mel, nullptr,
      ene_cw + LAYER_W, ene_cb + Fc, ene_lng + Fc, ene_lnb + Fc,
      ene_lw, ene_lb, o_ep, Tc);

  // 5) duration predictor (input = x directly, length S)
  conv_ln_kernel<false><<<gridS, 256, 0, stream>>>(
      x, nullptr, nullptr, nullptr, nullptr, nullptr,
      dur_cw, dur_cb, dur_lng, dur_lnb, w_buf, Sc);
  conv_ln_proj_kernel<false><<<gridS, 256, 0, stream>>>(
      w_buf, nullptr, sm,
      dur_cw + LAYER_W, dur_cb + Fc, dur_lng + Fc, dur_lnb + Fc,
      dur_lw, dur_lb, o_logd, Sc);

  // 6) final output
  final_kernel<<<Bc * Tc, 256, 0, stream>>>(
      x, w_idx, w_mel, o_pp, o_ep, pc2_w, pc2_b, ec2_w, ec2_b, o_out);
}

// Round 2
// 540.197 us; speedup vs baseline: 4.0383x; 4.0383x over previous
//
#include <hip/hip_runtime.h>
#include <cstdint>
#include <cstddef>

// Problem constants (match reference)
constexpr int Bc = 32;    // batch
constexpr int Sc = 512;   // source length
constexpr int Hc = 256;   // hidden
constexpr int Fc = 256;   // filter
constexpr int Tc = 2048;  // max mel length
constexpr int Kc = 3;     // conv kernel
constexpr float EPSc = 1e-5f;

// MFMA types (per cdna_hip_programming.md §3: bf16 frags as short8)
typedef __attribute__((ext_vector_type(8))) short bf16x8;
typedef __attribute__((ext_vector_type(4))) float f32x4;
typedef unsigned long long ull;
struct alignas(16) U16 { ull a, b; };

// LDS strides (shorts). 264: +8 pad -> ds_read_b128 conflict-free (132 dw, %32=4).
// 268 for bf16 output staging: (134 dw, 4 rows=536, %32=24) -> b16 writes conflict-free.
constexpr int ALD = 264;
constexpr int OLD = 268;

// ---- output layout (flat f32) ----
constexpr size_t O_OUT   = 0;                                   // (B,T,H)
constexpr size_t O_PP    = O_OUT  + (size_t)Bc*Tc*Hc;           // (B,T)
constexpr size_t O_EP    = O_PP   + (size_t)Bc*Tc;              // (B,T)
constexpr size_t O_LOGD  = O_EP   + (size_t)Bc*Tc;              // (B,S)
constexpr size_t O_DUR   = O_LOGD + (size_t)Bc*Sc;              // (B,S)
constexpr size_t O_MLEN  = O_DUR  + (size_t)Bc*Sc;              // (B,)
constexpr size_t O_MMASK = O_MLEN + (size_t)Bc;                 // (B,T)

// ---- workspace layout (bytes) ----
constexpr size_t W_CUM = 0;                 // int[B*S]
constexpr size_t W_MEL = 0x10000;           // int[B]
constexpr size_t W_IDX = 0x10100;           // int[B*T]
constexpr size_t W_WT  = 0x60000;           // short[6][256][768]  (2.25 MB)
constexpr size_t W_BUF = 0x2A0000;          // short[B*T*F] bf16 buffer (32 MB)
constexpr size_t WTSZ  = (size_t)Fc * 768;  // shorts per prepped weight tensor

__device__ __forceinline__ short f2bf(float f) {
  union { float f; unsigned u; } a; a.f = f;
  unsigned r = a.u + 0x7FFFu + ((a.u >> 16) & 1u);   // RNE
  return (short)(r >> 16);
}

// ============================================================
// 0) weight prep: w[k][ci][co] f32 -> w_t[co][k*256+ci] bf16, 6 tensors
// ============================================================
__global__ __launch_bounds__(256) void wprep_kernel(
    const float* __restrict__ pit, const float* __restrict__ ene,
    const float* __restrict__ dur, short* __restrict__ wt) {
  __shared__ float tile[32][33];
  int z = blockIdx.z;                         // pred*2 + layer
  const float* base = (z >> 1) == 0 ? pit : (z >> 1) == 1 ? ene : dur;
  const float* w = base + (size_t)(z & 1) * Kc * Fc * Fc;   // [768][256]
  short* out = wt + (size_t)z * WTSZ;                        // [256][768]
  int kci0 = blockIdx.x * 32, co0 = blockIdx.y * 32;
  int j = threadIdx.x & 31, i0 = threadIdx.x >> 5;
  #pragma unroll
  for (int p = 0; p < 4; p++) {
    int i = i0 + p * 8;
    tile[i][j] = w[(size_t)(kci0 + i) * Fc + co0 + j];
  }
  __syncthreads();
  #pragma unroll
  for (int p = 0; p < 4; p++) {
    int i = i0 + p * 8;
    out[(size_t)(co0 + i) * 768 + kci0 + j] = f2bf(tile[j][i]);
  }
}

// ============================================================
// 1) per-batch inclusive scan of durations + dur/mel_len outputs
// ============================================================
__global__ void scan_kernel(const int* __restrict__ dur, int* __restrict__ cum,
                            int* __restrict__ mel_i, float* __restrict__ dur_out,
                            float* __restrict__ mlen_out) {
  int b = blockIdx.x;
  int lane = threadIdx.x;                 // blockDim.x == 64
  const int per = Sc / 64;                // 8
  int base = b * Sc + lane * per;
  int v[per];
  int s = 0;
  #pragma unroll
  for (int i = 0; i < per; i++) { v[i] = dur[base + i]; s += v[i]; }
  int pre = s;
  #pragma unroll
  for (int d = 1; d < 64; d <<= 1) {
    int o = __shfl_up(pre, d, 64);
    if (lane >= d) pre += o;
  }
  int run = pre - s;
  #pragma unroll
  for (int i = 0; i < per; i++) {
    run += v[i];
    cum[base + i] = run;
    dur_out[base + i] = (float)v[i];
  }
  if (lane == 63) { mel_i[b] = run; mlen_out[b] = (float)run; }
}

// ============================================================
// 2) searchsorted(cum, t, 'right') -> idx ; mel_mask output
// ============================================================
__global__ void idx_kernel(const int* __restrict__ cum, const int* __restrict__ mel_i,
                           int* __restrict__ idx, float* __restrict__ mmask) {
  int gid = blockIdx.x * blockDim.x + threadIdx.x;   // B*T threads
  int b = gid / Tc, t = gid % Tc;
  const int* c = cum + b * Sc;
  int lo = 0, hi = Sc;
  while (lo < hi) {
    int mid = (lo + hi) >> 1;
    if (c[mid] <= t) lo = mid + 1; else hi = mid;
  }
  int i = lo > (Sc - 1) ? (Sc - 1) : lo;
  idx[gid] = i;
  mmask[gid] = (t < mel_i[b]) ? 0.0f : 1.0f;
}

// ============================================================
// Layer-1: conv1d(K=3) + bias + ReLU + LN via MFMA.
// Block: 256 thr (4 waves). Tile M=64 pos x N=256 ch. K=768.
// GATHER: input row t = valid * (x[b,idx[t],:] + sc*scw + scb), else x rows.
// Output: bf16 buffer [b][t][256].
// ============================================================
template <bool GATHER>
__global__ __launch_bounds__(256) void conv1_mfma_kernel(
    const float* __restrict__ x, const float* __restrict__ sc,
    const float* __restrict__ scw, const float* __restrict__ scb,
    const int* __restrict__ idx, const int* __restrict__ mel_i,
    const short* __restrict__ wt, const float* __restrict__ cb,
    const float* __restrict__ lng, const float* __restrict__ lnb,
    short* __restrict__ hout, int N) {
  __shared__ short a_lds[66 * ALD];
  __shared__ float part_s[64][4];
  __shared__ float part_s2[64][4];
  __shared__ float smean[64], srstd[64];

  const int tid = threadIdx.x;
  const int b = blockIdx.y;
  const int t0 = blockIdx.x * 64;
  const int lane = tid & 63, wv = tid >> 6;
  const int l15 = lane & 15, quad = lane >> 4;

  const int mel = GATHER ? mel_i[b] : 0;

  // ---- stage input rows t0-1 .. t0+64 as bf16 ----
  {
    const int c2 = (tid & 127) * 2;
    const int ro = tid >> 7;
    for (int it = 0; it < 33; it++) {
      int r = it * 2 + ro;
      int t = t0 + r - 1;
      float vx = 0.f, vy = 0.f;
      if (t >= 0 && t < N) {
        if (GATHER) {
          if (t < mel) {
            int i = idx[b * Tc + t];
            const float* xr = x + ((size_t)b * Sc + i) * Hc + c2;
            float s_ = sc[b * Sc + i];
            vx = xr[0] + s_ * scw[c2]     + scb[c2];
            vy = xr[1] + s_ * scw[c2 + 1] + scb[c2 + 1];
          }
        } else {
          const float* xr = x + ((size_t)b * N + t) * Hc + c2;
          vx = xr[0]; vy = xr[1];
        }
      }
      unsigned pk = (unsigned)(unsigned short)f2bf(vx) |
                    ((unsigned)(unsigned short)f2bf(vy) << 16);
      *(unsigned*)&a_lds[r * ALD + c2] = pk;
    }
  }
  __syncthreads();

  // ---- K-loop ----
  f32x4 acc[4][4];
  #pragma unroll
  for (int i = 0; i < 4; i++)
    #pragma unroll
    for (int j = 0; j < 4; j++) acc[i][j] = (f32x4){0.f, 0.f, 0.f, 0.f};

  const short* wbase = wt + (size_t)(wv * 64 + l15) * 768 + quad * 8;
  for (int kb = 0; kb < 24; kb++) {
    const int kk = kb >> 3, ci0 = (kb & 7) * 32;
    bf16x8 bv[4], av[4];
    #pragma unroll
    for (int nt = 0; nt < 4; nt++)
      bv[nt] = *(const bf16x8*)(wbase + (size_t)nt * 16 * 768 + kb * 32);
    #pragma unroll
    for (int mt = 0; mt < 4; mt++)
      av[mt] = *(const bf16x8*)&a_lds[(mt * 16 + l15 + kk) * ALD + ci0 + quad * 8];
    #pragma unroll
    for (int mt = 0; mt < 4; mt++)
      #pragma unroll
      for (int nt = 0; nt < 4; nt++)
        acc[mt][nt] = __builtin_amdgcn_mfma_f32_16x16x32_bf16(av[mt], bv[nt], acc[mt][nt], 0, 0, 0);
  }

  // ---- epilogue: bias + ReLU + LN stats ----
  float cbv[4], gv[4], bv2[4];
  #pragma unroll
  for (int nt = 0; nt < 4; nt++) {
    int ch = wv * 64 + nt * 16 + l15;
    cbv[nt] = cb[ch]; gv[nt] = lng[ch]; bv2[nt] = lnb[ch];
  }
  #pragma unroll
  for (int mt = 0; mt < 4; mt++)
    #pragma unroll
    for (int r = 0; r < 4; r++) {
      float s = 0.f, s2 = 0.f;
      #pragma unroll
      for (int nt = 0; nt < 4; nt++) {
        float v = fmaxf(acc[mt][nt][r] + cbv[nt], 0.f);
        acc[mt][nt][r] = v;
        s += v; s2 += v * v;
      }
      #pragma unroll
      for (int d = 1; d <= 8; d <<= 1) {
        s += __shfl_xor(s, d, 64);
        s2 += __shfl_xor(s2, d, 64);
      }
      if (l15 == 0) {
        int p = mt * 16 + quad * 4 + r;
        part_s[p][wv] = s; part_s2[p][wv] = s2;
      }
    }
  __syncthreads();
  if (tid < 64) {
    float s  = part_s[tid][0] + part_s[tid][1] + part_s[tid][2] + part_s[tid][3];
    float s2 = part_s2[tid][0] + part_s2[tid][1] + part_s2[tid][2] + part_s2[tid][3];
    float m = s * (1.f / Fc);
    float var = s2 * (1.f / Fc) - m * m;
    smean[tid] = m; srstd[tid] = rsqrtf(var + EPSc);
  }
  __syncthreads();

  // ---- apply LN, stage bf16 in LDS (stride OLD), coalesced store ----
  #pragma unroll
  for (int mt = 0; mt < 4; mt++)
    #pragma unroll
    for (int r = 0; r < 4; r++) {
      int p = mt * 16 + quad * 4 + r;
      float m = smean[p], rs = srstd[p];
      #pragma unroll
      for (int nt = 0; nt < 4; nt++) {
        float v = (acc[mt][nt][r] - m) * rs * gv[nt] + bv2[nt];
        a_lds[p * OLD + wv * 64 + nt * 16 + l15] = f2bf(v);
      }
    }
  __syncthreads();
  {
    int p = tid >> 2, c0 = (tid & 3) * 64;
    const short* src = &a_lds[p * OLD + c0];
    short* dst = hout + ((size_t)b * N + t0 + p) * 256 + c0;
    #pragma unroll
    for (int i = 0; i < 8; i++) {
      ull lo = *(const ull*)(src + i * 8);
      ull hi = *(const ull*)(src + i * 8 + 4);
      U16 v; v.a = lo; v.b = hi;
      *(U16*)(dst + i * 8) = v;
    }
  }
}

// ============================================================
// Layer-2: conv1d + bias + ReLU + LN + (h @ lw + lb) + mask -> pred
// Input: bf16 buffer. MASK_MEL: mask = t >= mel_len, else src_mask.
// ============================================================
template <bool MASK_MEL>
__global__ __launch_bounds__(256) void conv2_proj_mfma_kernel(
    const short* __restrict__ hin, const int* __restrict__ mel_i,
    const unsigned char* __restrict__ src_mask,
    const short* __restrict__ wt, const float* __restrict__ cb,
    const float* __restrict__ lng, const float* __restrict__ lnb,
    const float* __restrict__ lw, const float* __restrict__ lb,
    float* __restrict__ pred, int N) {
  __shared__ short a_lds[66 * ALD];
  __shared__ float part_s[64][4];
  __shared__ float part_s2[64][4];
  __shared__ float part_p[64][4];
  __shared__ float smean[64], srstd[64];

  const int tid = threadIdx.x;
  const int b = blockIdx.y;
  const int t0 = blockIdx.x * 64;
  const int lane = tid & 63, wv = tid >> 6;
  const int l15 = lane & 15, quad = lane >> 4;

  // ---- stage bf16 rows ----
  {
    int r0 = tid >> 5, c0 = (tid & 31) * 8;
    #pragma unroll
    for (int it = 0; it < 9; it++) {
      int r = it * 8 + r0;
      if (r < 66) {
        int t = t0 + r - 1;
        U16 v; v.a = 0; v.b = 0;
        if (t >= 0 && t < N) v = *(const U16*)(hin + ((size_t)b * N + t) * 256 + c0);
        *(U16*)&a_lds[r * ALD + c0] = v;
      }
    }
  }
  __syncthreads();

  // ---- K-loop (identical to layer 1) ----
  f32x4 acc[4][4];
  #pragma unroll
  for (int i = 0; i < 4; i++)
    #pragma unroll
    for (int j = 0; j < 4; j++) acc[i][j] = (f32x4){0.f, 0.f, 0.f, 0.f};

  const short* wbase = wt + (size_t)(wv * 64 + l15) * 768 + quad * 8;
  for (int kb = 0; kb < 24; kb++) {
    const int kk = kb >> 3, ci0 = (kb & 7) * 32;
    bf16x8 bv[4], av[4];
    #pragma unroll
    for (int nt = 0; nt < 4; nt++)
      bv[nt] = *(const bf16x8*)(wbase + (size_t)nt * 16 * 768 + kb * 32);
    #pragma unroll
    for (int mt = 0; mt < 4; mt++)
      av[mt] = *(const bf16x8*)&a_lds[(mt * 16 + l15 + kk) * ALD + ci0 + quad * 8];
    #pragma unroll
    for (int mt = 0; mt < 4; mt++)
      #pragma unroll
      for (int nt = 0; nt < 4; nt++)
        acc[mt][nt] = __builtin_amdgcn_mfma_f32_16x16x32_bf16(av[mt], bv[nt], acc[mt][nt], 0, 0, 0);
  }

  // ---- epilogue: bias + ReLU + LN stats ----
  float cbv[4], gv[4], bv2[4], lwv[4];
  #pragma unroll
  for (int nt = 0; nt < 4; nt++) {
    int ch = wv * 64 + nt * 16 + l15;
    cbv[nt] = cb[ch]; gv[nt] = lng[ch]; bv2[nt] = lnb[ch]; lwv[nt] = lw[ch];
  }
  #pragma unroll
  for (int mt = 0; mt < 4; mt++)
    #pragma unroll
    for (int r = 0; r < 4; r++) {
      float s = 0.f, s2 = 0.f;
      #pragma unroll
      for (int nt = 0; nt < 4; nt++) {
        float v = fmaxf(acc[mt][nt][r] + cbv[nt], 0.f);
        acc[mt][nt][r] = v;
        s += v; s2 += v * v;
      }
      #pragma unroll
      for (int d = 1; d <= 8; d <<= 1) {
        s += __shfl_xor(s, d, 64);
        s2 += __shfl_xor(s2, d, 64);
      }
      if (l15 == 0) {
        int p = mt * 16 + quad * 4 + r;
        part_s[p][wv] = s; part_s2[p][wv] = s2;
      }
    }
  __syncthreads();
  if (tid < 64) {
    float s  = part_s[tid][0] + part_s[tid][1] + part_s[tid][2] + part_s[tid][3];
    float s2 = part_s2[tid][0] + part_s2[tid][1] + part_s2[tid][2] + part_s2[tid][3];
    float m = s * (1.f / Fc);
    float var = s2 * (1.f / Fc) - m * m;
    smean[tid] = m; srstd[tid] = rsqrtf(var + EPSc);
  }
  __syncthreads();

  // ---- LN apply + projection reduce ----
  #pragma unroll
  for (int mt = 0; mt < 4; mt++)
    #pragma unroll
    for (int r = 0; r < 4; r++) {
      int p = mt * 16 + quad * 4 + r;
      float m = smean[p], rs = srstd[p];
      float s = 0.f;
      #pragma unroll
      for (int nt = 0; nt < 4; nt++) {
        float v = (acc[mt][nt][r] - m) * rs * gv[nt] + bv2[nt];
        s += v * lwv[nt];
      }
      #pragma unroll
      for (int d = 1; d <= 8; d <<= 1) s += __shfl_xor(s, d, 64);
      if (l15 == 0) part_p[p][wv] = s;
    }
  __syncthreads();
  if (tid < 64) {
    float o = part_p[tid][0] + part_p[tid][1] + part_p[tid][2] + part_p[tid][3] + lb[0];
    int t = t0 + tid;
    bool masked;
    if (MASK_MEL) masked = !(t < mel_i[b]);
    else          masked = (src_mask[b * N + t] != 0);
    pred[(size_t)b * N + t] = masked ? 0.f : o;
  }
}

// ============================================================
// out = xe + pp*pc2_w + pc2_b + ep*ec2_w + ec2_b
// ============================================================
__global__ __launch_bounds__(256) void final_kernel(
    const float* __restrict__ x, const int* __restrict__ idx,
    const int* __restrict__ mel_i,
    const float* __restrict__ pp, const float* __restrict__ ep,
    const float* __restrict__ pc2_w, const float* __restrict__ pc2_b,
    const float* __restrict__ ec2_w, const float* __restrict__ ec2_b,
    float* __restrict__ out) {
  int bt = blockIdx.x;                  // B*T blocks
  int b = bt / Tc, t = bt % Tc;
  int c = threadIdx.x;
  int i = idx[bt];
  float xe = (t < mel_i[b]) ? x[((size_t)b * Sc + i) * Hc + c] : 0.0f;
  float o = xe + pp[bt] * pc2_w[c] + pc2_b[c] + ep[bt] * ec2_w[c] + ec2_b[c];
  out[(size_t)bt * Hc + c] = o;
}

// ============================================================
extern "C" void kernel_launch(void* const* d_in, const int* in_sizes, int n_in,
                              void* d_out, int out_size, void* d_ws, size_t ws_size,
                              hipStream_t stream) {
  const float* x          = (const float*)d_in[0];
  const unsigned char* sm = (const unsigned char*)d_in[1];
  const float* src_pitch  = (const float*)d_in[3];
  const float* src_energy = (const float*)d_in[4];
  const int*   src_dur    = (const int*)d_in[5];

  const float* dur_cw = (const float*)d_in[7];
  const float* dur_cb = (const float*)d_in[8];
  const float* dur_lng= (const float*)d_in[9];
  const float* dur_lnb= (const float*)d_in[10];
  const float* dur_lw = (const float*)d_in[11];
  const float* dur_lb = (const float*)d_in[12];

  const float* pit_cw = (const float*)d_in[13];
  const float* pit_cb = (const float*)d_in[14];
  const float* pit_lng= (const float*)d_in[15];
  const float* pit_lnb= (const float*)d_in[16];
  const float* pit_lw = (const float*)d_in[17];
  const float* pit_lb = (const float*)d_in[18];

  const float* ene_cw = (const float*)d_in[19];
  const float* ene_cb = (const float*)d_in[20];
  const float* ene_lng= (const float*)d_in[21];
  const float* ene_lnb= (const float*)d_in[22];
  const float* ene_lw = (const float*)d_in[23];
  const float* ene_lb = (const float*)d_in[24];

  const float* pc1_w = (const float*)d_in[25];
  const float* pc1_b = (const float*)d_in[26];
  const float* pc2_w = (const float*)d_in[27];
  const float* pc2_b = (const float*)d_in[28];
  const float* ec1_w = (const float*)d_in[29];
  const float* ec1_b = (const float*)d_in[30];
  const float* ec2_w = (const float*)d_in[31];
  const float* ec2_b = (const float*)d_in[32];

  float* out = (float*)d_out;
  float* o_out   = out + O_OUT;
  float* o_pp    = out + O_PP;
  float* o_ep    = out + O_EP;
  float* o_logd  = out + O_LOGD;
  float* o_dur   = out + O_DUR;
  float* o_mlen  = out + O_MLEN;
  float* o_mmask = out + O_MMASK;

  char* ws = (char*)d_ws;
  int*   w_cum = (int*)(ws + W_CUM);
  int*   w_mel = (int*)(ws + W_MEL);
  int*   w_idx = (int*)(ws + W_IDX);
  short* w_wt  = (short*)(ws + W_WT);
  short* w_buf = (short*)(ws + W_BUF);

  // 0) weight prep (independent)
  wprep_kernel<<<dim3(24, 8, 6), 256, 0, stream>>>(pit_cw, ene_cw, dur_cw, w_wt);

  // 1) scan + dur/mel_len outputs
  scan_kernel<<<Bc, 64, 0, stream>>>(src_dur, w_cum, w_mel, o_dur, o_mlen);

  // 2) searchsorted + mel_mask output
  idx_kernel<<<(Bc * Tc) / 256, 256, 0, stream>>>(w_cum, w_mel, w_idx, o_mmask);

  dim3 gridT(Tc / 64, Bc);
  dim3 gridS(Sc / 64, Bc);

  // 3) pitch predictor
  conv1_mfma_kernel<true><<<gridT, 256, 0, stream>>>(
      x, src_pitch, pc1_w, pc1_b, w_idx, w_mel,
      w_wt + 0 * WTSZ, pit_cb, pit_lng, pit_lnb, w_buf, Tc);
  conv2_proj_mfma_kernel<true><<<gridT, 256, 0, stream>>>(
      w_buf, w_mel, nullptr,
      w_wt + 1 * WTSZ, pit_cb + Fc, pit_lng + Fc, pit_lnb + Fc,
      pit_lw, pit_lb, o_pp, Tc);

  // 4) energy predictor
  conv1_mfma_kernel<true><<<gridT, 256, 0, stream>>>(
      x, src_energy, ec1_w, ec1_b, w_idx, w_mel,
      w_wt + 2 * WTSZ, ene_cb, ene_lng, ene_lnb, w_buf, Tc);
  conv2_proj_mfma_kernel<true><<<gridT, 256, 0, stream>>>(
      w_buf, w_mel, nullptr,
      w_wt + 3 * WTSZ, ene_cb + Fc, ene_lng + Fc, ene_lnb + Fc,
      ene_lw, ene_lb, o_ep, Tc);

  // 5) duration predictor (input = x directly, length S)
  conv1_mfma_kernel<false><<<gridS, 256, 0, stream>>>(
      x, nullptr, nullptr, nullptr, nullptr, nullptr,
      w_wt + 4 * WTSZ, dur_cb, dur_lng, dur_lnb, w_buf, Sc);
  conv2_proj_mfma_kernel<false><<<gridS, 256, 0, stream>>>(
      w_buf, nullptr, sm,
      w_wt + 5 * WTSZ, dur_cb + Fc, dur_lng + Fc, dur_lnb + Fc,
      dur_lw, dur_lb, o_logd, Sc);

  // 6) final output
  final_kernel<<<Bc * Tc, 256, 0, stream>>>(
      x, w_idx, w_mel, o_pp, o_ep, pc2_w, pc2_b, ec2_w, ec2_b, o_out);
}

// Round 3
// 501.154 us; speedup vs baseline: 4.3530x; 1.0779x over previous
//
#include <hip/hip_runtime.h>
#include <cstdint>
#include <cstddef>

// Problem constants (match reference)
constexpr int Bc = 32;    // batch
constexpr int Sc = 512;   // source length
constexpr int Hc = 256;   // hidden
constexpr int Fc = 256;   // filter
constexpr int Tc = 2048;  // max mel length
constexpr int Kc = 3;     // conv kernel
constexpr float EPSc = 1e-5f;

// MFMA types
typedef __attribute__((ext_vector_type(8))) short bf16x8;
typedef __attribute__((ext_vector_type(4))) float f32x4;
typedef unsigned long long ull;
struct alignas(16) U16 { ull a, b; };

// LDS strides (shorts)
constexpr int ALD = 264;
constexpr int OLD = 268;

// ---- output layout (flat f32) ----
constexpr size_t O_OUT   = 0;                                   // (B,T,H)
constexpr size_t O_PP    = O_OUT  + (size_t)Bc*Tc*Hc;           // (B,T)
constexpr size_t O_EP    = O_PP   + (size_t)Bc*Tc;              // (B,T)
constexpr size_t O_LOGD  = O_EP   + (size_t)Bc*Tc;              // (B,S)
constexpr size_t O_DUR   = O_LOGD + (size_t)Bc*Sc;              // (B,S)
constexpr size_t O_MLEN  = O_DUR  + (size_t)Bc*Sc;              // (B,)
constexpr size_t O_MMASK = O_MLEN + (size_t)Bc;                 // (B,T)

// ---- workspace layout (bytes) ----
constexpr size_t W_CUM = 0;                 // int[B*S]
constexpr size_t W_MEL = 0x10000;           // int[B]
constexpr size_t W_IDX = 0x10100;           // int[B*T]
constexpr size_t W_WT  = 0x60000;           // short[6][256][768]  (2.25 MB)
constexpr size_t W_BUF = 0x2A0000;          // short[B*T*F] bf16 buffer (32 MB)
constexpr size_t WTSZ  = (size_t)Fc * 768;  // shorts per prepped weight tensor

__device__ __forceinline__ short f2bf(float f) {
  union { float f; unsigned u; } a; a.f = f;
  unsigned r = a.u + 0x7FFFu + ((a.u >> 16) & 1u);   // RNE
  return (short)(r >> 16);
}

// ============================================================
// 0) weight prep: w[k][ci][co] f32 -> w_t[co][k*256+ci] bf16, 6 tensors
// ============================================================
__global__ __launch_bounds__(256) void wprep_kernel(
    const float* __restrict__ pit, const float* __restrict__ ene,
    const float* __restrict__ dur, short* __restrict__ wt) {
  __shared__ float tile[32][33];
  int z = blockIdx.z;                         // pred*2 + layer
  const float* base = (z >> 1) == 0 ? pit : (z >> 1) == 1 ? ene : dur;
  const float* w = base + (size_t)(z & 1) * Kc * Fc * Fc;   // [768][256]
  short* out = wt + (size_t)z * WTSZ;                        // [256][768]
  int kci0 = blockIdx.x * 32, co0 = blockIdx.y * 32;
  int j = threadIdx.x & 31, i0 = threadIdx.x >> 5;
  #pragma unroll
  for (int p = 0; p < 4; p++) {
    int i = i0 + p * 8;
    tile[i][j] = w[(size_t)(kci0 + i) * Fc + co0 + j];
  }
  __syncthreads();
  #pragma unroll
  for (int p = 0; p < 4; p++) {
    int i = i0 + p * 8;
    out[(size_t)(co0 + i) * 768 + kci0 + j] = f2bf(tile[j][i]);
  }
}

// ============================================================
// 1) per-batch inclusive scan of durations + dur/mel_len outputs
// ============================================================
__global__ void scan_kernel(const int* __restrict__ dur, int* __restrict__ cum,
                            int* __restrict__ mel_i, float* __restrict__ dur_out,
                            float* __restrict__ mlen_out) {
  int b = blockIdx.x;
  int lane = threadIdx.x;                 // blockDim.x == 64
  const int per = Sc / 64;                // 8
  int base = b * Sc + lane * per;
  int v[per];
  int s = 0;
  #pragma unroll
  for (int i = 0; i < per; i++) { v[i] = dur[base + i]; s += v[i]; }
  int pre = s;
  #pragma unroll
  for (int d = 1; d < 64; d <<= 1) {
    int o = __shfl_up(pre, d, 64);
    if (lane >= d) pre += o;
  }
  int run = pre - s;
  #pragma unroll
  for (int i = 0; i < per; i++) {
    run += v[i];
    cum[base + i] = run;
    dur_out[base + i] = (float)v[i];
  }
  if (lane == 63) { mel_i[b] = run; mlen_out[b] = (float)run; }
}

// ============================================================
// 2) searchsorted(cum, t, 'right') -> idx ; mel_mask output
// ============================================================
__global__ void idx_kernel(const int* __restrict__ cum, const int* __restrict__ mel_i,
                           int* __restrict__ idx, float* __restrict__ mmask) {
  int gid = blockIdx.x * blockDim.x + threadIdx.x;   // B*T threads
  int b = gid / Tc, t = gid % Tc;
  const int* c = cum + b * Sc;
  int lo = 0, hi = Sc;
  while (lo < hi) {
    int mid = (lo + hi) >> 1;
    if (c[mid] <= t) lo = mid + 1; else hi = mid;
  }
  int i = lo > (Sc - 1) ? (Sc - 1) : lo;
  idx[gid] = i;
  mmask[gid] = (t < mel_i[b]) ? 0.0f : 1.0f;
}

// ============================================================
// Layer-1: conv1d(K=3) + bias + ReLU + LN via MFMA.
// Block: 256 thr (4 waves). Tile M=64 pos x N=256 ch. K=768.
// ============================================================
template <bool GATHER>
__global__ __launch_bounds__(256) void conv1_mfma_kernel(
    const float* __restrict__ x, const float* __restrict__ sc,
    const float* __restrict__ scw, const float* __restrict__ scb,
    const int* __restrict__ idx, const int* __restrict__ mel_i,
    const short* __restrict__ wt, const float* __restrict__ cb,
    const float* __restrict__ lng, const float* __restrict__ lnb,
    short* __restrict__ hout, int N) {
  __shared__ short a_lds[66 * ALD];
  __shared__ int s_idx[66];
  __shared__ float s_sc[66];
  __shared__ float part_s[64][4];
  __shared__ float part_s2[64][4];
  __shared__ float smean[64], srstd[64];

  const int tid = threadIdx.x;
  const int b = blockIdx.y;
  const int t0 = blockIdx.x * 64;
  const int lane = tid & 63, wv = tid >> 6;
  const int l15 = lane & 15, quad = lane >> 4;

  // ---- phase A: cooperative idx/sc preload (2 latency rounds total) ----
  if (GATHER) {
    if (tid < 66) {
      int t = t0 + tid - 1;
      bool v = (t >= 0 && t < N && t < mel_i[b]);
      int i = v ? idx[b * Tc + t] : -1;
      s_idx[tid] = i;
      s_sc[tid] = v ? sc[b * Sc + i] : 0.0f;
    }
    __syncthreads();
  }

  // ---- phase B: branch-free batched row staging (thread = row x 4ch) ----
  {
    const int r0 = tid >> 6;             // 0..3
    const int c4 = (tid & 63) * 4;       // float4 channel offset
    float4 scw4 = {0, 0, 0, 0}, scb4 = {0, 0, 0, 0};
    if (GATHER) {
      scw4 = *(const float4*)(scw + c4);
      scb4 = *(const float4*)(scb + c4);
    }
    #pragma unroll
    for (int it = 0; it < 17; it++) {
      int r = it * 4 + r0;               // 0..67
      if (r < 66) {
        float4 v = {0, 0, 0, 0};
        if (GATHER) {
          int i = s_idx[r];
          int is = i < 0 ? 0 : i;
          float4 xv = *(const float4*)(x + ((size_t)b * Sc + is) * Hc + c4);
          float s_ = s_sc[r];
          if (i >= 0) {
            v.x = xv.x + s_ * scw4.x + scb4.x;
            v.y = xv.y + s_ * scw4.y + scb4.y;
            v.z = xv.z + s_ * scw4.z + scb4.z;
            v.w = xv.w + s_ * scw4.w + scb4.w;
          }
        } else {
          int t = t0 + r - 1;
          int ts = t < 0 ? 0 : (t > N - 1 ? N - 1 : t);
          float4 xv = *(const float4*)(x + ((size_t)b * N + ts) * Hc + c4);
          if (t >= 0 && t < N) v = xv;
        }
        unsigned lo = (unsigned)(unsigned short)f2bf(v.x) |
                      ((unsigned)(unsigned short)f2bf(v.y) << 16);
        unsigned hi = (unsigned)(unsigned short)f2bf(v.z) |
                      ((unsigned)(unsigned short)f2bf(v.w) << 16);
        uint2 pk; pk.x = lo; pk.y = hi;
        *(uint2*)&a_lds[r * ALD + c4] = pk;
      }
    }
  }
  __syncthreads();

  // ---- K-loop with 2-stage B prefetch ----
  f32x4 acc[4][4];
  #pragma unroll
  for (int i = 0; i < 4; i++)
    #pragma unroll
    for (int j = 0; j < 4; j++) acc[i][j] = (f32x4){0.f, 0.f, 0.f, 0.f};

  const short* wp = wt + (size_t)(wv * 64 + l15) * 768 + quad * 8;
  bf16x8 vb0[4], vb1[4];
  #pragma unroll
  for (int nt = 0; nt < 4; nt++) vb0[nt] = *(const bf16x8*)(wp + nt * 12288);

  #pragma unroll 1
  for (int kb = 0; kb < 24; kb += 2) {
    #pragma unroll
    for (int nt = 0; nt < 4; nt++) vb1[nt] = *(const bf16x8*)(wp + 32 + nt * 12288);
    {
      const int kk = kb >> 3, ci0 = (kb & 7) * 32;
      bf16x8 av[4];
      #pragma unroll
      for (int mt = 0; mt < 4; mt++)
        av[mt] = *(const bf16x8*)&a_lds[(mt * 16 + l15 + kk) * ALD + ci0 + quad * 8];
      #pragma unroll
      for (int mt = 0; mt < 4; mt++)
        #pragma unroll
        for (int nt = 0; nt < 4; nt++)
          acc[mt][nt] = __builtin_amdgcn_mfma_f32_16x16x32_bf16(av[mt], vb0[nt], acc[mt][nt], 0, 0, 0);
    }
    #pragma unroll
    for (int nt = 0; nt < 4; nt++) vb0[nt] = *(const bf16x8*)(wp + 64 + nt * 12288);
    {
      const int kb1 = kb + 1;
      const int kk = kb1 >> 3, ci0 = (kb1 & 7) * 32;
      bf16x8 av[4];
      #pragma unroll
      for (int mt = 0; mt < 4; mt++)
        av[mt] = *(const bf16x8*)&a_lds[(mt * 16 + l15 + kk) * ALD + ci0 + quad * 8];
      #pragma unroll
      for (int mt = 0; mt < 4; mt++)
        #pragma unroll
        for (int nt = 0; nt < 4; nt++)
          acc[mt][nt] = __builtin_amdgcn_mfma_f32_16x16x32_bf16(av[mt], vb1[nt], acc[mt][nt], 0, 0, 0);
    }
    wp += 64;
  }

  // ---- epilogue: bias + ReLU + LN stats ----
  float cbv[4], gv[4], bv2[4];
  #pragma unroll
  for (int nt = 0; nt < 4; nt++) {
    int ch = wv * 64 + nt * 16 + l15;
    cbv[nt] = cb[ch]; gv[nt] = lng[ch]; bv2[nt] = lnb[ch];
  }
  #pragma unroll
  for (int mt = 0; mt < 4; mt++)
    #pragma unroll
    for (int r = 0; r < 4; r++) {
      float s = 0.f, s2 = 0.f;
      #pragma unroll
      for (int nt = 0; nt < 4; nt++) {
        float v = fmaxf(acc[mt][nt][r] + cbv[nt], 0.f);
        acc[mt][nt][r] = v;
        s += v; s2 += v * v;
      }
      #pragma unroll
      for (int d = 1; d <= 8; d <<= 1) {
        s += __shfl_xor(s, d, 64);
        s2 += __shfl_xor(s2, d, 64);
      }
      if (l15 == 0) {
        int p = mt * 16 + quad * 4 + r;
        part_s[p][wv] = s; part_s2[p][wv] = s2;
      }
    }
  __syncthreads();
  if (tid < 64) {
    float s  = part_s[tid][0] + part_s[tid][1] + part_s[tid][2] + part_s[tid][3];
    float s2 = part_s2[tid][0] + part_s2[tid][1] + part_s2[tid][2] + part_s2[tid][3];
    float m = s * (1.f / Fc);
    float var = s2 * (1.f / Fc) - m * m;
    smean[tid] = m; srstd[tid] = rsqrtf(var + EPSc);
  }
  __syncthreads();

  // ---- apply LN, stage bf16 in LDS (stride OLD), coalesced store ----
  #pragma unroll
  for (int mt = 0; mt < 4; mt++)
    #pragma unroll
    for (int r = 0; r < 4; r++) {
      int p = mt * 16 + quad * 4 + r;
      float m = smean[p], rs = srstd[p];
      #pragma unroll
      for (int nt = 0; nt < 4; nt++) {
        float v = (acc[mt][nt][r] - m) * rs * gv[nt] + bv2[nt];
        a_lds[p * OLD + wv * 64 + nt * 16 + l15] = f2bf(v);
      }
    }
  __syncthreads();
  {
    int p = tid >> 2, c0 = (tid & 3) * 64;
    const short* src = &a_lds[p * OLD + c0];
    short* dst = hout + ((size_t)b * N + t0 + p) * 256 + c0;
    #pragma unroll
    for (int i = 0; i < 8; i++) {
      ull lo = *(const ull*)(src + i * 8);
      ull hi = *(const ull*)(src + i * 8 + 4);
      U16 v; v.a = lo; v.b = hi;
      *(U16*)(dst + i * 8) = v;
    }
  }
}

// ============================================================
// Layer-2: conv1d + bias + ReLU + LN + (h @ lw + lb) + mask -> pred
// ============================================================
template <bool MASK_MEL>
__global__ __launch_bounds__(256) void conv2_proj_mfma_kernel(
    const short* __restrict__ hin, const int* __restrict__ mel_i,
    const unsigned char* __restrict__ src_mask,
    const short* __restrict__ wt, const float* __restrict__ cb,
    const float* __restrict__ lng, const float* __restrict__ lnb,
    const float* __restrict__ lw, const float* __restrict__ lb,
    float* __restrict__ pred, int N) {
  __shared__ short a_lds[66 * ALD];
  __shared__ float part_s[64][4];
  __shared__ float part_s2[64][4];
  __shared__ float part_p[64][4];
  __shared__ float smean[64], srstd[64];

  const int tid = threadIdx.x;
  const int b = blockIdx.y;
  const int t0 = blockIdx.x * 64;
  const int lane = tid & 63, wv = tid >> 6;
  const int l15 = lane & 15, quad = lane >> 4;

  // ---- stage bf16 rows (branch-free clamped loads) ----
  {
    int r0 = tid >> 5, c0 = (tid & 31) * 8;
    #pragma unroll
    for (int it = 0; it < 9; it++) {
      int r = it * 8 + r0;
      if (r < 66) {
        int t = t0 + r - 1;
        int ts = t < 0 ? 0 : (t > N - 1 ? N - 1 : t);
        U16 v = *(const U16*)(hin + ((size_t)b * N + ts) * 256 + c0);
        if (!(t >= 0 && t < N)) { v.a = 0; v.b = 0; }
        *(U16*)&a_lds[r * ALD + c0] = v;
      }
    }
  }
  __syncthreads();

  // ---- K-loop with 2-stage B prefetch ----
  f32x4 acc[4][4];
  #pragma unroll
  for (int i = 0; i < 4; i++)
    #pragma unroll
    for (int j = 0; j < 4; j++) acc[i][j] = (f32x4){0.f, 0.f, 0.f, 0.f};

  const short* wp = wt + (size_t)(wv * 64 + l15) * 768 + quad * 8;
  bf16x8 vb0[4], vb1[4];
  #pragma unroll
  for (int nt = 0; nt < 4; nt++) vb0[nt] = *(const bf16x8*)(wp + nt * 12288);

  #pragma unroll 1
  for (int kb = 0; kb < 24; kb += 2) {
    #pragma unroll
    for (int nt = 0; nt < 4; nt++) vb1[nt] = *(const bf16x8*)(wp + 32 + nt * 12288);
    {
      const int kk = kb >> 3, ci0 = (kb & 7) * 32;
      bf16x8 av[4];
      #pragma unroll
      for (int mt = 0; mt < 4; mt++)
        av[mt] = *(const bf16x8*)&a_lds[(mt * 16 + l15 + kk) * ALD + ci0 + quad * 8];
      #pragma unroll
      for (int mt = 0; mt < 4; mt++)
        #pragma unroll
        for (int nt = 0; nt < 4; nt++)
          acc[mt][nt] = __builtin_amdgcn_mfma_f32_16x16x32_bf16(av[mt], vb0[nt], acc[mt][nt], 0, 0, 0);
    }
    #pragma unroll
    for (int nt = 0; nt < 4; nt++) vb0[nt] = *(const bf16x8*)(wp + 64 + nt * 12288);
    {
      const int kb1 = kb + 1;
      const int kk = kb1 >> 3, ci0 = (kb1 & 7) * 32;
      bf16x8 av[4];
      #pragma unroll
      for (int mt = 0; mt < 4; mt++)
        av[mt] = *(const bf16x8*)&a_lds[(mt * 16 + l15 + kk) * ALD + ci0 + quad * 8];
      #pragma unroll
      for (int mt = 0; mt < 4; mt++)
        #pragma unroll
        for (int nt = 0; nt < 4; nt++)
          acc[mt][nt] = __builtin_amdgcn_mfma_f32_16x16x32_bf16(av[mt], vb1[nt], acc[mt][nt], 0, 0, 0);
    }
    wp += 64;
  }

  // ---- epilogue: bias + ReLU + LN stats ----
  float cbv[4], gv[4], bv2[4], lwv[4];
  #pragma unroll
  for (int nt = 0; nt < 4; nt++) {
    int ch = wv * 64 + nt * 16 + l15;
    cbv[nt] = cb[ch]; gv[nt] = lng[ch]; bv2[nt] = lnb[ch]; lwv[nt] = lw[ch];
  }
  #pragma unroll
  for (int mt = 0; mt < 4; mt++)
    #pragma unroll
    for (int r = 0; r < 4; r++) {
      float s = 0.f, s2 = 0.f;
      #pragma unroll
      for (int nt = 0; nt < 4; nt++) {
        float v = fmaxf(acc[mt][nt][r] + cbv[nt], 0.f);
        acc[mt][nt][r] = v;
        s += v; s2 += v * v;
      }
      #pragma unroll
      for (int d = 1; d <= 8; d <<= 1) {
        s += __shfl_xor(s, d, 64);
        s2 += __shfl_xor(s2, d, 64);
      }
      if (l15 == 0) {
        int p = mt * 16 + quad * 4 + r;
        part_s[p][wv] = s; part_s2[p][wv] = s2;
      }
    }
  __syncthreads();
  if (tid < 64) {
    float s  = part_s[tid][0] + part_s[tid][1] + part_s[tid][2] + part_s[tid][3];
    float s2 = part_s2[tid][0] + part_s2[tid][1] + part_s2[tid][2] + part_s2[tid][3];
    float m = s * (1.f / Fc);
    float var = s2 * (1.f / Fc) - m * m;
    smean[tid] = m; srstd[tid] = rsqrtf(var + EPSc);
  }
  __syncthreads();

  // ---- LN apply + projection reduce ----
  #pragma unroll
  for (int mt = 0; mt < 4; mt++)
    #pragma unroll
    for (int r = 0; r < 4; r++) {
      int p = mt * 16 + quad * 4 + r;
      float m = smean[p], rs = srstd[p];
      float s = 0.f;
      #pragma unroll
      for (int nt = 0; nt < 4; nt++) {
        float v = (acc[mt][nt][r] - m) * rs * gv[nt] + bv2[nt];
        s += v * lwv[nt];
      }
      #pragma unroll
      for (int d = 1; d <= 8; d <<= 1) s += __shfl_xor(s, d, 64);
      if (l15 == 0) part_p[p][wv] = s;
    }
  __syncthreads();
  if (tid < 64) {
    float o = part_p[tid][0] + part_p[tid][1] + part_p[tid][2] + part_p[tid][3] + lb[0];
    int t = t0 + tid;
    bool masked;
    if (MASK_MEL) masked = !(t < mel_i[b]);
    else          masked = (src_mask[b * N + t] != 0);
    pred[(size_t)b * N + t] = masked ? 0.f : o;
  }
}

// ============================================================
// out = xe + pp*pc2_w + pc2_b + ep*ec2_w + ec2_b
// ============================================================
__global__ __launch_bounds__(256) void final_kernel(
    const float* __restrict__ x, const int* __restrict__ idx,
    const int* __restrict__ mel_i,
    const float* __restrict__ pp, const float* __restrict__ ep,
    const float* __restrict__ pc2_w, const float* __restrict__ pc2_b,
    const float* __restrict__ ec2_w, const float* __restrict__ ec2_b,
    float* __restrict__ out) {
  int bt = blockIdx.x;                  // B*T blocks
  int b = bt / Tc, t = bt % Tc;
  int c = threadIdx.x;
  int i = idx[bt];
  float xe = (t < mel_i[b]) ? x[((size_t)b * Sc + i) * Hc + c] : 0.0f;
  float o = xe + pp[bt] * pc2_w[c] + pc2_b[c] + ep[bt] * ec2_w[c] + ec2_b[c];
  out[(size_t)bt * Hc + c] = o;
}

// ============================================================
extern "C" void kernel_launch(void* const* d_in, const int* in_sizes, int n_in,
                              void* d_out, int out_size, void* d_ws, size_t ws_size,
                              hipStream_t stream) {
  const float* x          = (const float*)d_in[0];
  const unsigned char* sm = (const unsigned char*)d_in[1];
  const float* src_pitch  = (const float*)d_in[3];
  const float* src_energy = (const float*)d_in[4];
  const int*   src_dur    = (const int*)d_in[5];

  const float* dur_cw = (const float*)d_in[7];
  const float* dur_cb = (const float*)d_in[8];
  const float* dur_lng= (const float*)d_in[9];
  const float* dur_lnb= (const float*)d_in[10];
  const float* dur_lw = (const float*)d_in[11];
  const float* dur_lb = (const float*)d_in[12];

  const float* pit_cw = (const float*)d_in[13];
  const float* pit_cb = (const float*)d_in[14];
  const float* pit_lng= (const float*)d_in[15];
  const float* pit_lnb= (const float*)d_in[16];
  const float* pit_lw = (const float*)d_in[17];
  const float* pit_lb = (const float*)d_in[18];

  const float* ene_cw = (const float*)d_in[19];
  const float* ene_cb = (const float*)d_in[20];
  const float* ene_lng= (const float*)d_in[21];
  const float* ene_lnb= (const float*)d_in[22];
  const float* ene_lw = (const float*)d_in[23];
  const float* ene_lb = (const float*)d_in[24];

  const float* pc1_w = (const float*)d_in[25];
  const float* pc1_b = (const float*)d_in[26];
  const float* pc2_w = (const float*)d_in[27];
  const float* pc2_b = (const float*)d_in[28];
  const float* ec1_w = (const float*)d_in[29];
  const float* ec1_b = (const float*)d_in[30];
  const float* ec2_w = (const float*)d_in[31];
  const float* ec2_b = (const float*)d_in[32];

  float* out = (float*)d_out;
  float* o_out   = out + O_OUT;
  float* o_pp    = out + O_PP;
  float* o_ep    = out + O_EP;
  float* o_logd  = out + O_LOGD;
  float* o_dur   = out + O_DUR;
  float* o_mlen  = out + O_MLEN;
  float* o_mmask = out + O_MMASK;

  char* ws = (char*)d_ws;
  int*   w_cum = (int*)(ws + W_CUM);
  int*   w_mel = (int*)(ws + W_MEL);
  int*   w_idx = (int*)(ws + W_IDX);
  short* w_wt  = (short*)(ws + W_WT);
  short* w_buf = (short*)(ws + W_BUF);

  // 0) weight prep (independent)
  wprep_kernel<<<dim3(24, 8, 6), 256, 0, stream>>>(pit_cw, ene_cw, dur_cw, w_wt);

  // 1) scan + dur/mel_len outputs
  scan_kernel<<<Bc, 64, 0, stream>>>(src_dur, w_cum, w_mel, o_dur, o_mlen);

  // 2) searchsorted + mel_mask output
  idx_kernel<<<(Bc * Tc) / 256, 256, 0, stream>>>(w_cum, w_mel, w_idx, o_mmask);

  dim3 gridT(Tc / 64, Bc);
  dim3 gridS(Sc / 64, Bc);

  // 3) pitch predictor
  conv1_mfma_kernel<true><<<gridT, 256, 0, stream>>>(
      x, src_pitch, pc1_w, pc1_b, w_idx, w_mel,
      w_wt + 0 * WTSZ, pit_cb, pit_lng, pit_lnb, w_buf, Tc);
  conv2_proj_mfma_kernel<true><<<gridT, 256, 0, stream>>>(
      w_buf, w_mel, nullptr,
      w_wt + 1 * WTSZ, pit_cb + Fc, pit_lng + Fc, pit_lnb + Fc,
      pit_lw, pit_lb, o_pp, Tc);

  // 4) energy predictor
  conv1_mfma_kernel<true><<<gridT, 256, 0, stream>>>(
      x, src_energy, ec1_w, ec1_b, w_idx, w_mel,
      w_wt + 2 * WTSZ, ene_cb, ene_lng, ene_lnb, w_buf, Tc);
  conv2_proj_mfma_kernel<true><<<gridT, 256, 0, stream>>>(
      w_buf, w_mel, nullptr,
      w_wt + 3 * WTSZ, ene_cb + Fc, ene_lng + Fc, ene_lnb + Fc,
      ene_lw, ene_lb, o_ep, Tc);

  // 5) duration predictor (input = x directly, length S)
  conv1_mfma_kernel<false><<<gridS, 256, 0, stream>>>(
      x, nullptr, nullptr, nullptr, nullptr, nullptr,
      w_wt + 4 * WTSZ, dur_cb, dur_lng, dur_lnb, w_buf, Sc);
  conv2_proj_mfma_kernel<false><<<gridS, 256, 0, stream>>>(
      w_buf, nullptr, sm,
      w_wt + 5 * WTSZ, dur_cb + Fc, dur_lng + Fc, dur_lnb + Fc,
      dur_lw, dur_lb, o_logd, Sc);

  // 6) final output
  final_kernel<<<Bc * Tc, 256, 0, stream>>>(
      x, w_idx, w_mel, o_pp, o_ep, pc2_w, pc2_b, ec2_w, ec2_b, o_out);
}